// Round 1
// baseline (811.220 us; speedup 1.0000x reference)
//
#include <hip/hip_runtime.h>
#include <hip/hip_bf16.h>

// Transformer decoder block, MI355X gfx950.
// Round 1: correctness-first bf16-MFMA implementation (m97-structure GEMMs,
// flash attention with swizzled LDS, fp32 softmax/LN/GELU/residuals).
//
// Workspace layout (MB offsets), peak 144 MB:
//   [0,2) Wq_bf [2,4) Wk_bf [4,6) Wv_bf [6,8) Wo_bf [8,16) W1_bf
//   [16,48) W2_bf [48,56) W3_bf [56,64) x_bf [64,72) q [72,80) k [80,88) v
//   [88,96) attn_bf [96,112) res1 [120,136) ln1_f32 [136,144) ln1_bf
//   h1_bf = [56,88) (reuses x_bf/q/k/v after attention)
//   h2_bf = [88,120) (reuses attn/res1 after LN1)
//   res2  = [56,72)  (reuses h1 after FFN2)

#define B_   2
#define T_   2048
#define D_   1024
#define H_   16
#define DK_  64
#define DFF_ 4096
#define M_   (B_ * T_)

using short8 = __attribute__((ext_vector_type(8))) short;
using f32x4  = __attribute__((ext_vector_type(4))) float;
using us4    = __attribute__((ext_vector_type(4))) unsigned short;

__device__ __forceinline__ unsigned short f2bf(float f) {
  unsigned u = __float_as_uint(f);
  u += 0x7FFFu + ((u >> 16) & 1u);   // RNE (inputs are finite/normal)
  return (unsigned short)(u >> 16);
}

#define GLDS16(g, l)                                                      \
  __builtin_amdgcn_global_load_lds(                                       \
      (const __attribute__((address_space(1))) unsigned int*)(g),         \
      (__attribute__((address_space(3))) unsigned int*)(l), 16, 0, 0)

// ---------------- fp32 -> bf16 convert ----------------
__global__ __launch_bounds__(256) void f2bf_k(const float* __restrict__ in,
                                              unsigned short* __restrict__ out,
                                              int n4) {
  int i = blockIdx.x * 256 + threadIdx.x;
  const int stride = gridDim.x * 256;
  for (; i < n4; i += stride) {
    const float4 v = ((const float4*)in)[i];
    us4 o;
    o[0] = f2bf(v.x); o[1] = f2bf(v.y); o[2] = f2bf(v.z); o[3] = f2bf(v.w);
    ((us4*)out)[i] = o;
  }
}

// ---------------- GEMM: C[m,n] = sum_k A[m,k] * W[n,k]  (+ epilogue) -------
// A: (M,K) bf16 row-major. W: (N,K) bf16 row-major ("B^T input").
// m97 structure: 128x128 tile, BK=32, 4 waves each 64x64, global_load_lds x16.
// MODE 0: QKV scatter -> bf16 (B,H,T,DK)
// MODE 1: += res (fp32), write fp32 row-major
// MODE 2: += bias, exact GELU, write bf16 row-major
// MODE 3: += bias += res, write fp32 row-major
template <int MODE>
__global__ __launch_bounds__(256) void gemm_bt(
    const unsigned short* __restrict__ A, const unsigned short* __restrict__ Bw,
    const float* __restrict__ bias, const float* __restrict__ res,
    void* __restrict__ outp, int N, int K) {
  __shared__ unsigned short lA[128 * 32];
  __shared__ unsigned short lB[128 * 32];
  const int tid  = threadIdx.x;
  const int lane = tid & 63;
  const int wave = tid >> 6;
  const int row0 = blockIdx.y << 7;
  const int col0 = blockIdx.x << 7;
  const int wr = (wave >> 1) << 6;
  const int wc = (wave & 1) << 6;
  const int r  = lane & 15;
  const int c8 = (lane >> 4) << 3;

  const f32x4 z4 = {0.f, 0.f, 0.f, 0.f};
  f32x4 acc[4][4];
#pragma unroll
  for (int m = 0; m < 4; ++m)
#pragma unroll
    for (int n = 0; n < 4; ++n) acc[m][n] = z4;

  const unsigned short* gA = A + (size_t)(row0 + (tid >> 2)) * K + (tid & 3) * 8;
  const unsigned short* gB = Bw + (size_t)(col0 + (tid >> 2)) * K + (tid & 3) * 8;
  const size_t rstep = (size_t)64 * K;
  unsigned short* lAd = lA + tid * 8;   // linear LDS dest (lane-ordered)
  unsigned short* lBd = lB + tid * 8;

  for (int kt = 0; kt < K; kt += 32) {
    GLDS16(gA + kt,         lAd);
    GLDS16(gA + kt + rstep, lAd + 2048);
    GLDS16(gB + kt,         lBd);
    GLDS16(gB + kt + rstep, lBd + 2048);
    __syncthreads();                      // drains vmcnt for the DMA
    short8 af[4], bf[4];
#pragma unroll
    for (int m = 0; m < 4; ++m)
      af[m] = *(const short8*)&lA[(wr + m * 16 + r) * 32 + c8];
#pragma unroll
    for (int n = 0; n < 4; ++n)
      bf[n] = *(const short8*)&lB[(wc + n * 16 + r) * 32 + c8];
#pragma unroll
    for (int m = 0; m < 4; ++m)
#pragma unroll
      for (int n = 0; n < 4; ++n)
        acc[m][n] = __builtin_amdgcn_mfma_f32_16x16x32_bf16(af[m], bf[n],
                                                            acc[m][n], 0, 0, 0);
    __syncthreads();
  }

  // epilogue — C/D layout: col = lane&15, row = (lane>>4)*4 + j  [m89/m91]
#pragma unroll
  for (int m = 0; m < 4; ++m) {
    const int gr0 = row0 + wr + m * 16 + ((lane >> 4) << 2);
#pragma unroll
    for (int n = 0; n < 4; ++n) {
      const int gc = col0 + wc + n * 16 + r;
#pragma unroll
      for (int j = 0; j < 4; ++j) {
        const int gr = gr0 + j;
        float v = acc[m][n][j];
        if (MODE == 0) {
          const int b = gr >> 11, t = gr & (T_ - 1);
          const int h = gc >> 6, d = gc & 63;
          ((unsigned short*)outp)[(((size_t)(b * H_ + h) * T_ + t) << 6) + d] =
              f2bf(v);
        } else if (MODE == 1) {
          const size_t o = (size_t)gr * N + gc;
          ((float*)outp)[o] = v + res[o];
        } else if (MODE == 2) {
          float xv = v + bias[gc];
          float g  = 0.5f * xv * (1.f + erff(xv * 0.70710678118654752f));
          ((unsigned short*)outp)[(size_t)gr * N + gc] = f2bf(g);
        } else {
          const size_t o = (size_t)gr * N + gc;
          ((float*)outp)[o] = v + bias[gc] + res[o];
        }
      }
    }
  }
}

// ---------------- causal flash attention ----------------
// Q,K,V bf16 (B,H,T,DK). Block = 4 waves, 64 q-rows (16/wave), KV tiles of 64.
// LDS swizzles (G4): rows are 128 B -> unswizzled would be 16-32-way conflicts.
__device__ __forceinline__ int swzK(int row, int col) {  // lK, lP
  return row * 64 + (col ^ ((row & 7) << 3));
}
__device__ __forceinline__ int swzV(int row, int col) {  // lV (transpose-write)
  return row * 64 + (col ^ (((row ^ (row >> 3)) & 7) << 3));
}

__global__ __launch_bounds__(256) void attn_k(
    const unsigned short* __restrict__ Q, const unsigned short* __restrict__ Kp,
    const unsigned short* __restrict__ Vp, unsigned short* __restrict__ O) {
  const int bh = blockIdx.y;
  const int qt = gridDim.x - 1 - blockIdx.x;  // heavy blocks launch first
  const int q0 = qt << 6;
  const size_t base = (size_t)bh * T_ * DK_;
  const unsigned short* Qb = Q + base;
  const unsigned short* Kb = Kp + base;
  const unsigned short* Vb = Vp + base;
  const int tid = threadIdx.x, lane = tid & 63, wave = tid >> 6;
  const int r = lane & 15, c8 = (lane >> 4) << 3;

  __shared__ unsigned short lK[64 * 64];  // [key][d], swzK
  __shared__ unsigned short lV[64 * 64];  // [d][key], swzV (transposed)
  __shared__ unsigned short lP[64 * 64];  // per-wave 16x64, swzK

  const short8 qf0 = *(const short8*)&Qb[(size_t)(q0 + wave * 16 + r) * 64 + c8];
  const short8 qf1 = *(const short8*)&Qb[(size_t)(q0 + wave * 16 + r) * 64 + 32 + c8];

  const f32x4 z4 = {0.f, 0.f, 0.f, 0.f};
  f32x4 o[4];
#pragma unroll
  for (int n = 0; n < 4; ++n) o[n] = z4;
  float mrow[4], lrow[4];
#pragma unroll
  for (int j = 0; j < 4; ++j) { mrow[j] = -1e30f; lrow[j] = 0.f; }

  const int kr = tid >> 3;                          // staging row (0..31)
  const int kc = ((tid & 7) * 8) ^ ((kr & 7) << 3); // pre-swizzled K source col
  const int vc = (tid & 7) * 8;

  for (int kt = 0; kt <= qt; ++kt) {
    __syncthreads();  // previous tile's reads complete before overwrite
    // K tile -> LDS (DMA, source-swizzled so linear LDS == swzK layout)
    GLDS16(&Kb[((size_t)kt * 64 + kr) * 64 + kc],      lK + tid * 8);
    GLDS16(&Kb[((size_t)kt * 64 + 32 + kr) * 64 + kc], lK + 2048 + tid * 8);
    // V tile -> regs -> transposed swizzled LDS
    const short8 v0 = *(const short8*)&Vb[((size_t)kt * 64 + kr) * 64 + vc];
    const short8 v1 = *(const short8*)&Vb[((size_t)kt * 64 + 32 + kr) * 64 + vc];
#pragma unroll
    for (int e = 0; e < 8; ++e) {
      const int d0 = vc + e;
      lV[swzV(d0, kr)]      = (unsigned short)v0[e];
      lV[swzV(d0, kr + 32)] = (unsigned short)v1[e];
    }
    __syncthreads();  // K DMA (vmcnt) + V writes (lgkmcnt) visible to all

    // S = Q K^T  (per wave: 16q x 64k)
    f32x4 s[4];
#pragma unroll
    for (int n = 0; n < 4; ++n) {
      const int krow = n * 16 + r;
      const short8 k0 = *(const short8*)&lK[swzK(krow, c8)];
      const short8 k1 = *(const short8*)&lK[swzK(krow, c8 + 32)];
      f32x4 z = z4;
      z = __builtin_amdgcn_mfma_f32_16x16x32_bf16(qf0, k0, z, 0, 0, 0);
      z = __builtin_amdgcn_mfma_f32_16x16x32_bf16(qf1, k1, z, 0, 0, 0);
      s[n] = z;
    }

    const bool diag = (kt == qt);
#pragma unroll
    for (int n = 0; n < 4; ++n)
#pragma unroll
      for (int j = 0; j < 4; ++j) {
        float sv = s[n][j] * 0.125f;  // 1/sqrt(64)
        if (diag) {
          const int kk = n * 16 + r;
          const int qq = wave * 16 + ((lane >> 4) << 2) + j;
          if (kk > qq) sv = -1e30f;
        }
        s[n][j] = sv;
      }

    // online softmax, rows live in 16-lane groups (C layout)
#pragma unroll
    for (int j = 0; j < 4; ++j) {
      float mx = fmaxf(fmaxf(s[0][j], s[1][j]), fmaxf(s[2][j], s[3][j]));
#pragma unroll
      for (int msk = 1; msk < 16; msk <<= 1) mx = fmaxf(mx, __shfl_xor(mx, msk));
      const float mnew = fmaxf(mrow[j], mx);
      const float c = __expf(mrow[j] - mnew);  // first tile: exp(-1e30)=0
      mrow[j] = mnew;
      float rs = 0.f;
#pragma unroll
      for (int n = 0; n < 4; ++n) {
        const float p = __expf(s[n][j] - mnew);
        s[n][j] = p;
        rs += p;
      }
#pragma unroll
      for (int msk = 1; msk < 16; msk <<= 1) rs += __shfl_xor(rs, msk);
      lrow[j] = lrow[j] * c + rs;
#pragma unroll
      for (int n = 0; n < 4; ++n) o[n][j] *= c;
    }

    // P -> bf16 -> LDS (per-wave region, swzK)
#pragma unroll
    for (int n = 0; n < 4; ++n)
#pragma unroll
      for (int j = 0; j < 4; ++j) {
        const int q  = ((lane >> 4) << 2) + j;
        const int kk = n * 16 + r;
        lP[wave * 1024 + swzK(q, kk)] = f2bf(s[n][j]);
      }
    asm volatile("s_waitcnt lgkmcnt(0)" ::: "memory");  // cross-lane same-wave

    // O += P V
    const short8 pa0 = *(const short8*)&lP[wave * 1024 + swzK(r, c8)];
    const short8 pa1 = *(const short8*)&lP[wave * 1024 + swzK(r, c8 + 32)];
#pragma unroll
    for (int n = 0; n < 4; ++n) {
      const int dr = n * 16 + r;
      const short8 vb0 = *(const short8*)&lV[swzV(dr, c8)];
      const short8 vb1 = *(const short8*)&lV[swzV(dr, c8 + 32)];
      o[n] = __builtin_amdgcn_mfma_f32_16x16x32_bf16(pa0, vb0, o[n], 0, 0, 0);
      o[n] = __builtin_amdgcn_mfma_f32_16x16x32_bf16(pa1, vb1, o[n], 0, 0, 0);
    }
  }

  // epilogue: O[b,t,h*64+d] bf16
  const int b = bh >> 4, h = bh & 15;
  float rinv[4];
#pragma unroll
  for (int j = 0; j < 4; ++j) rinv[j] = 1.f / lrow[j];
#pragma unroll
  for (int n = 0; n < 4; ++n)
#pragma unroll
    for (int j = 0; j < 4; ++j) {
      const int q = q0 + wave * 16 + ((lane >> 4) << 2) + j;
      const int d = n * 16 + r;
      O[((size_t)(b * T_ + q) * D_) + h * 64 + d] = f2bf(o[n][j] * rinv[j]);
    }
}

// ---------------- LayerNorm (row = 1024, fp32 in/out, optional bf16 copy) ---
__global__ __launch_bounds__(256) void ln_k(const float* __restrict__ in,
                                            const float* __restrict__ gam,
                                            const float* __restrict__ bet,
                                            float* __restrict__ o32,
                                            unsigned short* __restrict__ obf) {
  const int row = blockIdx.x;
  const int tid = threadIdx.x, lane = tid & 63, wave = tid >> 6;
  const float4 v = ((const float4*)(in + (size_t)row * D_))[tid];
  __shared__ float sm[8];
  float s = v.x + v.y + v.z + v.w;
#pragma unroll
  for (int m = 32; m >= 1; m >>= 1) s += __shfl_xor(s, m);
  if (lane == 0) sm[wave] = s;
  __syncthreads();
  const float mean = (sm[0] + sm[1] + sm[2] + sm[3]) * (1.f / 1024.f);
  const float dx = v.x - mean, dy = v.y - mean, dz = v.z - mean, dw = v.w - mean;
  float q = dx * dx + dy * dy + dz * dz + dw * dw;
#pragma unroll
  for (int m = 32; m >= 1; m >>= 1) q += __shfl_xor(q, m);
  if (lane == 0) sm[4 + wave] = q;
  __syncthreads();
  const float var = (sm[4] + sm[5] + sm[6] + sm[7]) * (1.f / 1024.f);
  const float inv = rsqrtf(var + 1e-5f);
  const float4 g = ((const float4*)gam)[tid];
  const float4 b = ((const float4*)bet)[tid];
  float4 y;
  y.x = dx * inv * g.x + b.x;
  y.y = dy * inv * g.y + b.y;
  y.z = dz * inv * g.z + b.z;
  y.w = dw * inv * g.w + b.w;
  ((float4*)(o32 + (size_t)row * D_))[tid] = y;
  if (obf) {
    us4 o;
    o[0] = f2bf(y.x); o[1] = f2bf(y.y); o[2] = f2bf(y.z); o[3] = f2bf(y.w);
    ((us4*)(obf + (size_t)row * D_))[tid] = o;
  }
}

// ---------------- launch ----------------
#define MB(x) ((size_t)(x) << 20)

extern "C" void kernel_launch(void* const* d_in, const int* in_sizes, int n_in,
                              void* d_out, int out_size, void* d_ws,
                              size_t ws_size, hipStream_t stream) {
  const float* x   = (const float*)d_in[0];
  const float* Wq  = (const float*)d_in[1];
  const float* Wk  = (const float*)d_in[2];
  const float* Wv  = (const float*)d_in[3];
  const float* Wo  = (const float*)d_in[4];
  const float* W1  = (const float*)d_in[5];
  const float* b1  = (const float*)d_in[6];
  const float* W2  = (const float*)d_in[7];
  const float* b2  = (const float*)d_in[8];
  const float* W3  = (const float*)d_in[9];
  const float* b3  = (const float*)d_in[10];
  const float* g1  = (const float*)d_in[11];
  const float* be1 = (const float*)d_in[12];
  const float* g2  = (const float*)d_in[13];
  const float* be2 = (const float*)d_in[14];
  float* out = (float*)d_out;

  char* w = (char*)d_ws;
  unsigned short* Wq_bf = (unsigned short*)(w + MB(0));
  unsigned short* Wk_bf = (unsigned short*)(w + MB(2));
  unsigned short* Wv_bf = (unsigned short*)(w + MB(4));
  unsigned short* Wo_bf = (unsigned short*)(w + MB(6));
  unsigned short* W1_bf = (unsigned short*)(w + MB(8));
  unsigned short* W2_bf = (unsigned short*)(w + MB(16));
  unsigned short* W3_bf = (unsigned short*)(w + MB(48));
  unsigned short* x_bf  = (unsigned short*)(w + MB(56));
  unsigned short* q_bf  = (unsigned short*)(w + MB(64));
  unsigned short* k_bf  = (unsigned short*)(w + MB(72));
  unsigned short* v_bf  = (unsigned short*)(w + MB(80));
  unsigned short* a_bf  = (unsigned short*)(w + MB(88));
  float*          res1  = (float*)(w + MB(96));
  float*          ln1f  = (float*)(w + MB(120));
  unsigned short* ln1bf = (unsigned short*)(w + MB(136));
  unsigned short* h1_bf = (unsigned short*)(w + MB(56));  // reuse x/q/k/v
  unsigned short* h2_bf = (unsigned short*)(w + MB(88));  // reuse attn/res1
  float*          res2  = (float*)(w + MB(56));           // reuse h1

  auto cvt = [&](const float* src, unsigned short* dst, int n) {
    const int n4 = n >> 2;
    int blocks = (n4 + 255) / 256;
    if (blocks > 2048) blocks = 2048;
    f2bf_k<<<dim3(blocks), dim3(256), 0, stream>>>(src, dst, n4);
  };
  cvt(x,  x_bf,  M_ * D_);
  cvt(Wq, Wq_bf, D_ * D_);
  cvt(Wk, Wk_bf, D_ * D_);
  cvt(Wv, Wv_bf, D_ * D_);
  cvt(Wo, Wo_bf, D_ * D_);
  cvt(W1, W1_bf, DFF_ * D_);
  cvt(W2, W2_bf, DFF_ * DFF_);
  cvt(W3, W3_bf, D_ * DFF_);

  const dim3 blk(256);
  const dim3 gD(D_ / 128, M_ / 128);     // N=1024 GEMMs
  const dim3 gF(DFF_ / 128, M_ / 128);   // N=4096 GEMMs

  gemm_bt<0><<<gD, blk, 0, stream>>>(x_bf, Wq_bf, nullptr, nullptr, q_bf, D_, D_);
  gemm_bt<0><<<gD, blk, 0, stream>>>(x_bf, Wk_bf, nullptr, nullptr, k_bf, D_, D_);
  gemm_bt<0><<<gD, blk, 0, stream>>>(x_bf, Wv_bf, nullptr, nullptr, v_bf, D_, D_);

  attn_k<<<dim3(T_ / 64, B_ * H_), blk, 0, stream>>>(q_bf, k_bf, v_bf, a_bf);

  gemm_bt<1><<<gD, blk, 0, stream>>>(a_bf, Wo_bf, nullptr, x, res1, D_, D_);
  ln_k<<<dim3(M_), blk, 0, stream>>>(res1, g1, be1, ln1f, ln1bf);

  gemm_bt<2><<<gF, blk, 0, stream>>>(ln1bf, W1_bf, b1, nullptr, h1_bf, DFF_, D_);
  gemm_bt<2><<<gF, blk, 0, stream>>>(h1_bf, W2_bf, b2, nullptr, h2_bf, DFF_, DFF_);
  gemm_bt<3><<<gD, blk, 0, stream>>>(h2_bf, W3_bf, b3, ln1f, res2, D_, DFF_);

  ln_k<<<dim3(M_), blk, 0, stream>>>(res2, g2, be2, out, nullptr);
}

// Round 5
// 649.783 us; speedup vs baseline: 1.2484x; 1.2484x over previous
//
#include <hip/hip_runtime.h>
#include <hip/hip_bf16.h>

// Transformer decoder block, MI355X gfx950. Round 5 (= round 3/4 source;
// rounds 2-4 never ran due to GPU acquisition timeouts).
//  - 256x256 8-phase GEMM (T2 swizzle + T3/T4 counted vmcnt + T5 setprio)
//    for QKV (fused N=3072), FFN1, FFN2, FFN3 (split-K=4 + reduce).
//    FIX A (r3): stB half-swap (B cols 0:64/64:128 were exchanged).
//    FIX B (r3): s_barrier after each counted vmcnt wait (per-wave vmcnt does
//           not cover other waves' global_load_lds; barrier publishes).
//  - attention KVBLK=128, exp2-domain softmax.
//  - fused fp32->bf16 convert; Wo on m97-structure kernel (known good).
//
// Workspace map (MB):  peak 136 MB
//  [0,8) x_bf (s1-2) -> ln1f [0,16) (s5-9)
//  [8,14) qkvw (s1-2), [14,16) Wo_bf (s1-4)
//  [16,24) W1 (s1-6), [24,56) W2 (s1-7), [56,64) W3 (s1-8)
//  [64,72) q,[72,80) k,[80,88) v (s2-3), [88,96) a_bf (s3-4)
//  res1 [64,80) (s4-5); h1 [96,128) (s6-7); h2 [64,96) (s7-8)
//  ln1bf [128,136) (s5-6); p0 [16,32) p1 [32,48) p2 [96,112) p3 [112,128) (s8-9)
//  res2 [80,96) (s9-10)

#define B_   2
#define T_   2048
#define D_   1024
#define H_   16
#define DK_  64
#define DFF_ 4096
#define M_   (B_ * T_)

using short8 = __attribute__((ext_vector_type(8))) short;
using f32x4  = __attribute__((ext_vector_type(4))) float;
using us4    = __attribute__((ext_vector_type(4))) unsigned short;

__device__ __forceinline__ unsigned short f2bf(float f) {
  unsigned u = __float_as_uint(f);
  u += 0x7FFFu + ((u >> 16) & 1u);  // RNE
  return (unsigned short)(u >> 16);
}
__device__ __forceinline__ us4 pack4(float4 v) {
  us4 o; o[0] = f2bf(v.x); o[1] = f2bf(v.y); o[2] = f2bf(v.z); o[3] = f2bf(v.w);
  return o;
}

#define GLDS16(g, l)                                                      \
  __builtin_amdgcn_global_load_lds(                                       \
      (const __attribute__((address_space(1))) unsigned int*)(g),         \
      (__attribute__((address_space(3))) unsigned int*)(l), 16, 0, 0)

#define SB   __builtin_amdgcn_s_barrier()
#define LG0  do { asm volatile("s_waitcnt lgkmcnt(0)" ::: "memory"); \
                  __builtin_amdgcn_sched_barrier(0); } while (0)
#define VMW2 do { asm volatile("s_waitcnt vmcnt(2)" ::: "memory");   \
                  __builtin_amdgcn_sched_barrier(0); } while (0)
#define VMW0 do { asm volatile("s_waitcnt vmcnt(0)" ::: "memory");   \
                  __builtin_amdgcn_sched_barrier(0); } while (0)
#define PR1  __builtin_amdgcn_s_setprio(1)
#define PR0  __builtin_amdgcn_s_setprio(0)

// ---------------- fused fp32 -> bf16 convert ----------------
__global__ __launch_bounds__(256) void cvt_all(
    const float* __restrict__ x,  const float* __restrict__ wq,
    const float* __restrict__ wk, const float* __restrict__ wv,
    const float* __restrict__ wo, const float* __restrict__ w1,
    const float* __restrict__ w2, const float* __restrict__ w3,
    us4* __restrict__ xb, us4* __restrict__ qkvw, us4* __restrict__ wob,
    us4* __restrict__ w1b, us4* __restrict__ w2b, us4* __restrict__ w3b) {
  int i = blockIdx.x * 256 + threadIdx.x;
  const int stride = gridDim.x * 256;
  for (; i < 8388608; i += stride) {
    const float4* s; us4* d; int off;
    if      (i < 1048576) { s = (const float4*)x;  d = xb;            off = i; }
    else if (i < 1310720) { s = (const float4*)wq; d = qkvw;          off = i - 1048576; }
    else if (i < 1572864) { s = (const float4*)wk; d = qkvw + 262144; off = i - 1310720; }
    else if (i < 1835008) { s = (const float4*)wv; d = qkvw + 524288; off = i - 1572864; }
    else if (i < 2097152) { s = (const float4*)wo; d = wob;           off = i - 1835008; }
    else if (i < 3145728) { s = (const float4*)w1; d = w1b;           off = i - 2097152; }
    else if (i < 7340032) { s = (const float4*)w2; d = w2b;           off = i - 3145728; }
    else                  { s = (const float4*)w3; d = w3b;           off = i - 7340032; }
    d[off] = pack4(s[off]);
  }
}

// ---------------- 256x256 8-phase GEMM ----------------
// C[m,n] = sum_k A[m,k]*Bw[n,k].  A:(M,ldk) Bw:(N,ldk) bf16.
// MODE 0: QKV scatter (N=3072) -> bf16 (B,H,T,DK) x3
// MODE 2: +bias, exact GELU -> bf16 row-major
// MODE 4: split-K partial -> fp32 (blockIdx.z selects split & k-range)
template <int MODE>
__global__ __launch_bounds__(512, 2) void gemm8p(
    const unsigned short* __restrict__ A, const unsigned short* __restrict__ Bw,
    const float* __restrict__ bias, unsigned short* __restrict__ oq,
    unsigned short* __restrict__ ok, unsigned short* __restrict__ ov,
    float* __restrict__ pLo, float* __restrict__ pHi,
    int N, int ldk, int klen) {
  extern __shared__ unsigned short sm[];
  unsigned short* lA = sm;           // [db][half][128][64] (swizzled)
  unsigned short* lB = sm + 32768;
  const int tid = threadIdx.x, lane = tid & 63, w = tid >> 6;
  const int wm = w >> 2, wn = w & 3;
  const int wnlo = (wn & 1) * 64, wnhi = wn >> 1;
  const int r16 = lane & 15, c8a = (lane >> 4) << 3;
  const int row0 = blockIdx.y << 8, col0 = blockIdx.x << 8;
  const int kb = (MODE == 4) ? blockIdx.z * klen : 0;

  // staging coords: thread t covers LDS (row = t>>3, colbyte=(t&7)*16);
  // global source col is pre-XOR'd so linear LDS == swizzled layout (m173).
  const int srow = tid >> 3;
  const int scol = ((tid & 7) * 8) ^ ((srow & 7) << 3);
  const size_t off0 = (size_t)srow * ldk + scol;
  const size_t off1 = (size_t)(srow + 64) * ldk + scol;

  auto stA = [&](int kt, int h) {
    const unsigned short* g =
        A + (size_t)(row0 + h * 128) * ldk + kb + (size_t)kt * 64;
    unsigned short* d = lA + ((kt & 1) * 2 + h) * 8192;
    GLDS16(g + off0, d + tid * 8);
    GLDS16(g + off1, d + 4096 + tid * 8);
  };
  auto stB = [&](int kt, int h) {
    const unsigned short* g =
        Bw + (size_t)(col0 + h * 128) * ldk + kb + (size_t)kt * 64;
    unsigned short* d = lB + ((kt & 1) * 2 + h) * 8192;
    GLDS16(g + off0, d + tid * 8);            // rows 0..63  -> LDS rows 0..63
    GLDS16(g + off1, d + 4096 + tid * 8);     // rows 64..127 -> 64..127
  };

  f32x4 acc[8][4];
#pragma unroll
  for (int m = 0; m < 8; ++m)
#pragma unroll
    for (int n = 0; n < 4; ++n) acc[m][n] = (f32x4){0.f, 0.f, 0.f, 0.f};

  short8 aR[4][2], bR[2][2];

#define LDA4(DB, MQ)                                                         \
  do {                                                                       \
    _Pragma("unroll") for (int mf_ = 0; mf_ < 4; ++mf_) {                    \
      const int rr = (MQ)*64 + mf_ * 16 + r16;                               \
      const int bb = ((DB)*2 + wm) * 8192 + rr * 64;                         \
      const int sw = (rr & 7) << 3;                                          \
      aR[mf_][0] = *(const short8*)&lA[bb + (c8a ^ sw)];                     \
      aR[mf_][1] = *(const short8*)&lA[bb + ((c8a + 32) ^ sw)];              \
    }                                                                        \
  } while (0)
#define LDB2(DB, NP)                                                         \
  do {                                                                       \
    _Pragma("unroll") for (int nf_ = 0; nf_ < 2; ++nf_) {                    \
      const int rr = wnlo + ((NP)*2 + nf_) * 16 + r16;                       \
      const int bb = ((DB)*2 + wnhi) * 8192 + rr * 64;                       \
      const int sw = (rr & 7) << 3;                                          \
      bR[nf_][0] = *(const short8*)&lB[bb + (c8a ^ sw)];                     \
      bR[nf_][1] = *(const short8*)&lB[bb + ((c8a + 32) ^ sw)];              \
    }                                                                        \
  } while (0)
#define MMQ(MQ, NP)                                                          \
  do {                                                                       \
    _Pragma("unroll") for (int mf_ = 0; mf_ < 4; ++mf_)                      \
    _Pragma("unroll") for (int nf_ = 0; nf_ < 2; ++nf_) {                    \
      f32x4 c_ = acc[(MQ)*4 + mf_][(NP)*2 + nf_];                            \
      c_ = __builtin_amdgcn_mfma_f32_16x16x32_bf16(aR[mf_][0], bR[nf_][0],   \
                                                   c_, 0, 0, 0);             \
      c_ = __builtin_amdgcn_mfma_f32_16x16x32_bf16(aR[mf_][1], bR[nf_][1],   \
                                                   c_, 0, 0, 0);             \
      acc[(MQ)*4 + mf_][(NP)*2 + nf_] = c_;                                  \
    }                                                                        \
  } while (0)
#define TAIL(MQ, NP) SB; LG0; PR1; MMQ(MQ, NP); PR0; SB

  const int nkt = klen >> 6;
  // prologue: K-tile 0, 4 half-tiles
  stA(0, 0); stA(0, 1); stB(0, 0); stB(0, 1);

  for (int i = 0; i < nkt; i += 2) {
    // ---- K-tile i (db=0) ----
    stA(i + 1, 0);
    VMW2;   // own tile-i loads landed (<=2 newest in flight)
    SB;     // publish ALL waves' tile-i DMA completion
    LDA4(0, 0); LDB2(0, 0);
    TAIL(0, 0);
    stA(i + 1, 1);
    LDB2(0, 1);
    TAIL(0, 1);
    stB(i + 1, 0);
    LDA4(0, 1);
    TAIL(1, 1);
    stB(i + 1, 1);
    LDB2(0, 0);
    TAIL(1, 0);
    // ---- K-tile i+1 (db=1) ----
    const bool more = (i + 2 < nkt);
    if (more) { stA(i + 2, 0); VMW2; } else { VMW0; }
    SB;
    LDA4(1, 0); LDB2(1, 0);
    TAIL(0, 0);
    if (more) stA(i + 2, 1);
    LDB2(1, 1);
    TAIL(0, 1);
    if (more) stB(i + 2, 0);
    LDA4(1, 1);
    TAIL(1, 1);
    if (more) stB(i + 2, 1);
    LDB2(1, 0);
    TAIL(1, 0);
  }

  // epilogue — C/D: col = lane&15, row = (lane>>4)*4 + j
#pragma unroll
  for (int am = 0; am < 8; ++am) {
    const int gr0 = row0 + wm * 128 + am * 16 + ((lane >> 4) << 2);
#pragma unroll
    for (int an = 0; an < 4; ++an) {
      const int gc = col0 + wn * 64 + an * 16 + r16;
#pragma unroll
      for (int j = 0; j < 4; ++j) {
        const int gr = gr0 + j;
        float v = acc[am][an][j];
        if (MODE == 0) {
          const int which = gc >> 10, c1 = gc & 1023;
          const int b = gr >> 11, t = gr & (T_ - 1);
          const int h = c1 >> 6, d = c1 & 63;
          unsigned short* dst = (which == 0) ? oq : (which == 1) ? ok : ov;
          dst[(((size_t)(b * H_ + h) * T_ + t) << 6) + d] = f2bf(v);
        } else if (MODE == 2) {
          float xv = v + bias[gc];
          float g  = 0.5f * xv * (1.f + erff(xv * 0.70710678118654752f));
          oq[(size_t)gr * N + gc] = f2bf(g);
        } else {  // MODE 4
          const int z = blockIdx.z;
          float* o = (z < 2) ? pLo + (size_t)z * (M_ * 1024)
                             : pHi + (size_t)(z - 2) * (M_ * 1024);
          o[(size_t)gr * 1024 + gc] = v;
        }
      }
    }
  }
#undef LDA4
#undef LDB2
#undef MMQ
#undef TAIL
}

// ---------------- m97-structure GEMM (Wo only): C = A*W^T + res ----------
__global__ __launch_bounds__(256) void gemm_bt(
    const unsigned short* __restrict__ A, const unsigned short* __restrict__ Bw,
    const float* __restrict__ res, float* __restrict__ outp, int N, int K) {
  __shared__ unsigned short lA[128 * 32];
  __shared__ unsigned short lB[128 * 32];
  const int tid = threadIdx.x, lane = tid & 63, wave = tid >> 6;
  const int row0 = blockIdx.y << 7, col0 = blockIdx.x << 7;
  const int wr = (wave >> 1) << 6, wc = (wave & 1) << 6;
  const int r = lane & 15, c8 = (lane >> 4) << 3;
  const f32x4 z4 = {0.f, 0.f, 0.f, 0.f};
  f32x4 acc[4][4];
#pragma unroll
  for (int m = 0; m < 4; ++m)
#pragma unroll
    for (int n = 0; n < 4; ++n) acc[m][n] = z4;
  const unsigned short* gA = A + (size_t)(row0 + (tid >> 2)) * K + (tid & 3) * 8;
  const unsigned short* gB = Bw + (size_t)(col0 + (tid >> 2)) * K + (tid & 3) * 8;
  const size_t rstep = (size_t)64 * K;
  unsigned short* lAd = lA + tid * 8;
  unsigned short* lBd = lB + tid * 8;
  for (int kt = 0; kt < K; kt += 32) {
    GLDS16(gA + kt, lAd);
    GLDS16(gA + kt + rstep, lAd + 2048);
    GLDS16(gB + kt, lBd);
    GLDS16(gB + kt + rstep, lBd + 2048);
    __syncthreads();
    short8 af[4], bf[4];
#pragma unroll
    for (int m = 0; m < 4; ++m)
      af[m] = *(const short8*)&lA[(wr + m * 16 + r) * 32 + c8];
#pragma unroll
    for (int n = 0; n < 4; ++n)
      bf[n] = *(const short8*)&lB[(wc + n * 16 + r) * 32 + c8];
#pragma unroll
    for (int m = 0; m < 4; ++m)
#pragma unroll
      for (int n = 0; n < 4; ++n)
        acc[m][n] = __builtin_amdgcn_mfma_f32_16x16x32_bf16(af[m], bf[n],
                                                            acc[m][n], 0, 0, 0);
    __syncthreads();
  }
#pragma unroll
  for (int m = 0; m < 4; ++m) {
    const int gr0 = row0 + wr + m * 16 + ((lane >> 4) << 2);
#pragma unroll
    for (int n = 0; n < 4; ++n) {
      const int gc = col0 + wc + n * 16 + r;
#pragma unroll
      for (int j = 0; j < 4; ++j) {
        const size_t o = (size_t)(gr0 + j) * N + gc;
        outp[o] = acc[m][n][j] + res[o];
      }
    }
  }
}

// ---------------- causal flash attention (KVBLK=128) ----------------
__global__ __launch_bounds__(256) void attn_k(
    const unsigned short* __restrict__ Q, const unsigned short* __restrict__ Kp,
    const unsigned short* __restrict__ Vp, unsigned short* __restrict__ O) {
  const int bh = blockIdx.y;
  const int qt = gridDim.x - 1 - blockIdx.x;  // heavy blocks first
  const int q0 = qt << 6;
  const size_t base = (size_t)bh * T_ * DK_;
  const unsigned short* Qb = Q + base;
  const unsigned short* Kb = Kp + base;
  const unsigned short* Vb = Vp + base;
  const int tid = threadIdx.x, lane = tid & 63, wave = tid >> 6;
  const int r = lane & 15, c8 = (lane >> 4) << 3;

  __shared__ unsigned short lK[128 * 64];   // [key][d]   swz
  __shared__ unsigned short lV[64 * 128];   // [d][key]   swz (transposed)
  __shared__ unsigned short lP[4 * 16 * 128];

  const short8 qf0 = *(const short8*)&Qb[(size_t)(q0 + wave * 16 + r) * 64 + c8];
  const short8 qf1 =
      *(const short8*)&Qb[(size_t)(q0 + wave * 16 + r) * 64 + 32 + c8];

  const f32x4 z4 = {0.f, 0.f, 0.f, 0.f};
  f32x4 o[4];
#pragma unroll
  for (int n = 0; n < 4; ++n) o[n] = z4;
  float mrow[4], lrow[4];
#pragma unroll
  for (int j = 0; j < 4; ++j) { mrow[j] = -1e30f; lrow[j] = 0.f; }

  const float SCL = 0.125f * 1.44269504088896f;  // 1/sqrt(64) * log2(e)
  const int krow = tid >> 3;                             // 0..31
  const int kcol = ((tid & 7) * 8) ^ ((krow & 7) << 3);  // pre-swizzled src

  const int niter = (q0 >> 7) + 1;
  for (int kt = 0; kt < niter; ++kt) {
    __syncthreads();
    const unsigned short* Kt = Kb + ((size_t)kt << 7) * 64;
    GLDS16(Kt + krow * 64 + kcol,         lK + tid * 8);
    GLDS16(Kt + (krow + 32) * 64 + kcol,  lK + 2048 + tid * 8);
    GLDS16(Kt + (krow + 64) * 64 + kcol,  lK + 4096 + tid * 8);
    GLDS16(Kt + (krow + 96) * 64 + kcol,  lK + 6144 + tid * 8);
    const unsigned short* Vt = Vb + ((size_t)kt << 7) * 64;
    short8 vld[4];
#pragma unroll
    for (int l = 0; l < 4; ++l)
      vld[l] = *(const short8*)&Vt[(size_t)((tid >> 3) + 32 * l) * 64 +
                                   (tid & 7) * 8];
#pragma unroll
    for (int l = 0; l < 4; ++l)
#pragma unroll
      for (int e = 0; e < 8; ++e) {
        const int dd = (tid & 7) * 8 + e, kv = (tid >> 3) + 32 * l;
        lV[dd * 128 + (kv ^ ((dd & 7) << 3))] = (unsigned short)vld[l][e];
      }
    __syncthreads();

    // S = Q K^T  (16q x 128k per wave)
    f32x4 s[8];
#pragma unroll
    for (int nf = 0; nf < 8; ++nf) {
      const int kr = nf * 16 + r;
      const int sw = (kr & 7) << 3;
      const short8 k0 = *(const short8*)&lK[kr * 64 + (c8 ^ sw)];
      const short8 k1 = *(const short8*)&lK[kr * 64 + ((c8 + 32) ^ sw)];
      f32x4 z = z4;
      z = __builtin_amdgcn_mfma_f32_16x16x32_bf16(qf0, k0, z, 0, 0, 0);
      z = __builtin_amdgcn_mfma_f32_16x16x32_bf16(qf1, k1, z, 0, 0, 0);
      s[nf] = z;
    }

    const bool tail = (kt == niter - 1);
#pragma unroll
    for (int nf = 0; nf < 8; ++nf)
#pragma unroll
      for (int j = 0; j < 4; ++j) {
        float sv = s[nf][j] * SCL;
        if (tail) {
          const int kg = (kt << 7) + nf * 16 + r;
          const int qg = q0 + wave * 16 + ((lane >> 4) << 2) + j;
          if (kg > qg) sv = -1e30f;
        }
        s[nf][j] = sv;
      }

    // online softmax (exp2 domain), rows in 16-lane groups
#pragma unroll
    for (int j = 0; j < 4; ++j) {
      float mx = s[0][j];
#pragma unroll
      for (int nf = 1; nf < 8; ++nf) mx = fmaxf(mx, s[nf][j]);
#pragma unroll
      for (int msk = 1; msk < 16; msk <<= 1) mx = fmaxf(mx, __shfl_xor(mx, msk));
      const float mnew = fmaxf(mrow[j], mx);
      const float c = exp2f(mrow[j] - mnew);
      mrow[j] = mnew;
      float rs = 0.f;
#pragma unroll
      for (int nf = 0; nf < 8; ++nf) {
        const float p = exp2f(s[nf][j] - mnew);
        s[nf][j] = p;
        rs += p;
      }
#pragma unroll
      for (int msk = 1; msk < 16; msk <<= 1) rs += __shfl_xor(rs, msk);
      lrow[j] = lrow[j] * c + rs;
#pragma unroll
      for (int n = 0; n < 4; ++n) o[n][j] *= c;
    }

    // P -> bf16 -> LDS (per-wave, swz)
    unsigned short* Pw = lP + wave * 2048;
#pragma unroll
    for (int nf = 0; nf < 8; ++nf)
#pragma unroll
      for (int j = 0; j < 4; ++j) {
        const int q = ((lane >> 4) << 2) + j, kk = nf * 16 + r;
        Pw[q * 128 + (kk ^ ((q & 7) << 3))] = f2bf(s[nf][j]);
      }
    asm volatile("s_waitcnt lgkmcnt(0)" ::: "memory");
    __builtin_amdgcn_sched_barrier(0);

    // O += P V
    short8 pa[4];
#pragma unroll
    for (int kh = 0; kh < 4; ++kh) {
      const int cc = kh * 32 + c8;
      pa[kh] = *(const short8*)&Pw[r * 128 + (cc ^ ((r & 7) << 3))];
    }
#pragma unroll
    for (int df = 0; df < 4; ++df) {
      const int dr = df * 16 + r;
      const int sw = (dr & 7) << 3;
#pragma unroll
      for (int kh = 0; kh < 4; ++kh) {
        const int cc = kh * 32 + c8;
        const short8 vb = *(const short8*)&lV[dr * 128 + (cc ^ sw)];
        o[df] = __builtin_amdgcn_mfma_f32_16x16x32_bf16(pa[kh], vb, o[df],
                                                        0, 0, 0);
      }
    }
  }

  const int b = bh >> 4, h = bh & 15;
  float rinv[4];
#pragma unroll
  for (int j = 0; j < 4; ++j) rinv[j] = 1.f / lrow[j];
#pragma unroll
  for (int n = 0; n < 4; ++n)
#pragma unroll
    for (int j = 0; j < 4; ++j) {
      const int q = q0 + wave * 16 + ((lane >> 4) << 2) + j;
      const int d = n * 16 + r;
      O[((size_t)(b * T_ + q) * D_) + h * 64 + d] = f2bf(o[n][j] * rinv[j]);
    }
}

// ---------------- split-K reduce + bias + residual ----------------
__global__ __launch_bounds__(256) void red_k(
    const float4* __restrict__ p0, const float4* __restrict__ p1,
    const float4* __restrict__ p2, const float4* __restrict__ p3,
    const float4* __restrict__ ln1, const float4* __restrict__ b3,
    float4* __restrict__ res2) {
  int i = blockIdx.x * 256 + threadIdx.x;
  const int stride = gridDim.x * 256;
  for (; i < M_ * 256; i += stride) {
    const float4 a = p0[i], b = p1[i], c = p2[i], d = p3[i], e = ln1[i];
    const float4 bb = b3[i & 255];
    float4 v;
    v.x = a.x + b.x + c.x + d.x + e.x + bb.x;
    v.y = a.y + b.y + c.y + d.y + e.y + bb.y;
    v.z = a.z + b.z + c.z + d.z + e.z + bb.z;
    v.w = a.w + b.w + c.w + d.w + e.w + bb.w;
    res2[i] = v;
  }
}

// ---------------- LayerNorm ----------------
__global__ __launch_bounds__(256) void ln_k(const float* __restrict__ in,
                                            const float* __restrict__ gam,
                                            const float* __restrict__ bet,
                                            float* __restrict__ o32,
                                            unsigned short* __restrict__ obf) {
  const int row = blockIdx.x;
  const int tid = threadIdx.x, lane = tid & 63, wave = tid >> 6;
  const float4 v = ((const float4*)(in + (size_t)row * D_))[tid];
  __shared__ float sm[8];
  float s = v.x + v.y + v.z + v.w;
#pragma unroll
  for (int m = 32; m >= 1; m >>= 1) s += __shfl_xor(s, m);
  if (lane == 0) sm[wave] = s;
  __syncthreads();
  const float mean = (sm[0] + sm[1] + sm[2] + sm[3]) * (1.f / 1024.f);
  const float dx = v.x - mean, dy = v.y - mean, dz = v.z - mean, dw = v.w - mean;
  float q = dx * dx + dy * dy + dz * dz + dw * dw;
#pragma unroll
  for (int m = 32; m >= 1; m >>= 1) q += __shfl_xor(q, m);
  if (lane == 0) sm[4 + wave] = q;
  __syncthreads();
  const float var = (sm[4] + sm[5] + sm[6] + sm[7]) * (1.f / 1024.f);
  const float inv = rsqrtf(var + 1e-5f);
  const float4 g = ((const float4*)gam)[tid];
  const float4 b = ((const float4*)bet)[tid];
  float4 y;
  y.x = dx * inv * g.x + b.x;
  y.y = dy * inv * g.y + b.y;
  y.z = dz * inv * g.z + b.z;
  y.w = dw * inv * g.w + b.w;
  ((float4*)(o32 + (size_t)row * D_))[tid] = y;
  if (obf) {
    us4 o;
    o[0] = f2bf(y.x); o[1] = f2bf(y.y); o[2] = f2bf(y.z); o[3] = f2bf(y.w);
    ((us4*)(obf + (size_t)row * D_))[tid] = o;
  }
}

// ---------------- launch ----------------
#define MB(x) ((size_t)(x) << 20)

extern "C" void kernel_launch(void* const* d_in, const int* in_sizes, int n_in,
                              void* d_out, int out_size, void* d_ws,
                              size_t ws_size, hipStream_t stream) {
  const float* x   = (const float*)d_in[0];
  const float* Wq  = (const float*)d_in[1];
  const float* Wk  = (const float*)d_in[2];
  const float* Wv  = (const float*)d_in[3];
  const float* Wo  = (const float*)d_in[4];
  const float* W1  = (const float*)d_in[5];
  const float* b1  = (const float*)d_in[6];
  const float* W2  = (const float*)d_in[7];
  const float* b2  = (const float*)d_in[8];
  const float* W3  = (const float*)d_in[9];
  const float* b3  = (const float*)d_in[10];
  const float* g1  = (const float*)d_in[11];
  const float* be1 = (const float*)d_in[12];
  const float* g2  = (const float*)d_in[13];
  const float* be2 = (const float*)d_in[14];
  float* out = (float*)d_out;

  char* w = (char*)d_ws;
  unsigned short* x_bf  = (unsigned short*)(w + MB(0));
  unsigned short* qkvw  = (unsigned short*)(w + MB(8));
  unsigned short* Wo_bf = (unsigned short*)(w + MB(14));
  unsigned short* W1_bf = (unsigned short*)(w + MB(16));
  unsigned short* W2_bf = (unsigned short*)(w + MB(24));
  unsigned short* W3_bf = (unsigned short*)(w + MB(56));
  unsigned short* q_bf  = (unsigned short*)(w + MB(64));
  unsigned short* k_bf  = (unsigned short*)(w + MB(72));
  unsigned short* v_bf  = (unsigned short*)(w + MB(80));
  unsigned short* a_bf  = (unsigned short*)(w + MB(88));
  float*          res1  = (float*)(w + MB(64));
  float*          ln1f  = (float*)(w + MB(0));
  unsigned short* ln1bf = (unsigned short*)(w + MB(128));
  unsigned short* h1_bf = (unsigned short*)(w + MB(96));
  unsigned short* h2_bf = (unsigned short*)(w + MB(64));
  float*          part0 = (float*)(w + MB(16));   // splits 0,1 (32 MB)
  float*          part2 = (float*)(w + MB(96));   // splits 2,3 (32 MB)
  float*          res2  = (float*)(w + MB(80));

  (void)hipFuncSetAttribute((const void*)gemm8p<0>,
      hipFuncAttributeMaxDynamicSharedMemorySize, 131072);
  (void)hipFuncSetAttribute((const void*)gemm8p<2>,
      hipFuncAttributeMaxDynamicSharedMemorySize, 131072);
  (void)hipFuncSetAttribute((const void*)gemm8p<4>,
      hipFuncAttributeMaxDynamicSharedMemorySize, 131072);

  cvt_all<<<dim3(2048), dim3(256), 0, stream>>>(
      x, Wq, Wk, Wv, Wo, W1, W2, W3, (us4*)x_bf, (us4*)qkvw, (us4*)Wo_bf,
      (us4*)W1_bf, (us4*)W2_bf, (us4*)W3_bf);

  // QKV: x(4096x1024) @ [Wq;Wk;Wv]^T (3072x1024) -> scatter
  gemm8p<0><<<dim3(12, 16), dim3(512), 131072, stream>>>(
      x_bf, qkvw, nullptr, q_bf, k_bf, v_bf, nullptr, nullptr,
      3072, 1024, 1024);

  attn_k<<<dim3(T_ / 64, B_ * H_), dim3(256), 0, stream>>>(q_bf, k_bf, v_bf,
                                                           a_bf);

  gemm_bt<<<dim3(8, 32), dim3(256), 0, stream>>>(a_bf, Wo_bf, x, res1, D_, D_);
  ln_k<<<dim3(M_), dim3(256), 0, stream>>>(res1, g1, be1, ln1f, ln1bf);

  gemm8p<2><<<dim3(16, 16), dim3(512), 131072, stream>>>(
      ln1bf, W1_bf, b1, h1_bf, nullptr, nullptr, nullptr, nullptr,
      DFF_, 1024, 1024);
  gemm8p<2><<<dim3(16, 16), dim3(512), 131072, stream>>>(
      h1_bf, W2_bf, b2, h2_bf, nullptr, nullptr, nullptr, nullptr,
      DFF_, 4096, 4096);
  gemm8p<4><<<dim3(4, 16, 4), dim3(512), 131072, stream>>>(
      h2_bf, W3_bf, nullptr, nullptr, nullptr, nullptr, part0, part2,
      D_, 4096, 1024);

  red_k<<<dim3(2048), dim3(256), 0, stream>>>(
      (const float4*)part0, (const float4*)(w + MB(32)),
      (const float4*)part2, (const float4*)(w + MB(112)),
      (const float4*)ln1f, (const float4*)b3, (float4*)res2);

  ln_k<<<dim3(M_), dim3(256), 0, stream>>>(res2, g2, be2, out, nullptr);
}